// Round 1
// baseline (671.970 us; speedup 1.0000x reference)
//
#include <hip/hip_runtime.h>
#include <hip/hip_bf16.h>

#define DIN 128
#define DH  128
#define DOUT 64
#define PAD 16                   // one atomic counter per 64B line

typedef __attribute__((ext_vector_type(8))) short short8;
typedef __attribute__((ext_vector_type(4))) float f32x4;

static __device__ __forceinline__ unsigned short f2bf(float f) {
    unsigned int u = __float_as_uint(f);
    u += 0x7FFFu + ((u >> 16) & 1u);   // RNE
    return (unsigned short)(u >> 16);
}
static __device__ __forceinline__ float bflo(unsigned int p) {
    return __uint_as_float(p << 16);
}
static __device__ __forceinline__ float bfhi(unsigned int p) {
    return __uint_as_float(p & 0xFFFF0000u);
}

// ---------------- weights: transpose + cast to bf16 ----------------
__global__ __launch_bounds__(256) void prep_w_kernel(const float* __restrict__ W1,
                                                     const float* __restrict__ W2,
                                                     const float* __restrict__ W3,
                                                     unsigned short* __restrict__ Wt1,
                                                     unsigned short* __restrict__ Wt2,
                                                     unsigned short* __restrict__ Wt3) {
    int i = blockIdx.x * 256 + threadIdx.x;
    if (i < 128 * 128) {
        int n = i >> 7, k = i & 127;
        Wt1[n * 128 + k] = f2bf(W1[k * 128 + n]);
        Wt2[n * 128 + k] = f2bf(W2[k * 128 + n]);
        if (n < 64) Wt3[n * 128 + k] = f2bf(W3[k * 64 + n]);
    }
}

// ---------------- degree (padded counters: deg_p[i*PAD]) ----------------
__global__ __launch_bounds__(256) void deg_init_kernel(int* __restrict__ deg_p, int n) {
    int i = blockIdx.x * 256 + threadIdx.x;
    if (i < n) deg_p[(size_t)i * PAD] = 1;   // self-loop
}
__global__ __launch_bounds__(256) void deg_count_kernel(const int* __restrict__ ei, int E,
                                                        int* __restrict__ deg_p) {
    int e = (blockIdx.x * 256 + threadIdx.x) * 2;
    if (e + 1 < E) {
        int d0 = ei[E + e], d1 = ei[E + e + 1];
        atomicAdd(&deg_p[(size_t)d0 * PAD], 1);
        atomicAdd(&deg_p[(size_t)d1 * PAD], 1);
    } else if (e < E) {
        atomicAdd(&deg_p[(size_t)ei[E + e] * PAD], 1);
    }
}

// ---------------- 3-phase exclusive scan of deg -> row_start ----------------
__global__ __launch_bounds__(256) void scan_block_sums(const int* __restrict__ deg_p,
                                                       int* __restrict__ bsum, int n) {
    __shared__ int s[256];
    int t = threadIdx.x, base = blockIdx.x * 1024;
    int v = 0;
    #pragma unroll
    for (int j = 0; j < 4; j++) {
        int idx = base + t * 4 + j;
        if (idx < n) v += deg_p[(size_t)idx * PAD];
    }
    s[t] = v; __syncthreads();
    for (int off = 128; off > 0; off >>= 1) {
        if (t < off) s[t] += s[t + off];
        __syncthreads();
    }
    if (t == 0) bsum[blockIdx.x] = s[0];
}

__global__ __launch_bounds__(256) void scan_bsum_kernel(int* __restrict__ bsum, int nb) {
    __shared__ int s[256];
    int t = threadIdx.x;
    s[t] = (t < nb) ? bsum[t] : 0; __syncthreads();
    for (int off = 1; off < 256; off <<= 1) {
        int v = (t >= off) ? s[t - off] : 0;
        __syncthreads();
        s[t] += v;
        __syncthreads();
    }
    if (t < nb) bsum[t] = (t > 0) ? s[t - 1] : 0;   // exclusive
}

__global__ __launch_bounds__(256) void scan_final_kernel(const int* __restrict__ deg_p,
                                                         const int* __restrict__ bsum_ex,
                                                         int* __restrict__ row_start,
                                                         float* __restrict__ dis,
                                                         int* __restrict__ cursor_p,
                                                         int* __restrict__ csr_src, int n) {
    __shared__ int s[256];
    int t = threadIdx.x, base = blockIdx.x * 1024;
    int d[4]; int local = 0;
    #pragma unroll
    for (int j = 0; j < 4; j++) {
        int idx = base + t * 4 + j;
        d[j] = (idx < n) ? deg_p[(size_t)idx * PAD] : 0;
        local += d[j];
    }
    s[t] = local; __syncthreads();
    for (int off = 1; off < 256; off <<= 1) {
        int v = (t >= off) ? s[t - off] : 0;
        __syncthreads();
        s[t] += v;
        __syncthreads();
    }
    int ex = ((t > 0) ? s[t - 1] : 0) + bsum_ex[blockIdx.x];
    #pragma unroll
    for (int j = 0; j < 4; j++) {
        int idx = base + t * 4 + j;
        if (idx < n) {
            row_start[idx] = ex;
            float di = rsqrtf((float)d[j]);
            dis[idx] = di;
            cursor_p[(size_t)idx * PAD] = ex + 1;   // slot 0 = self loop
            csr_src[ex] = idx;                      // self-loop entry (src = idx)
            if (idx == n - 1) row_start[n] = ex + d[j];
            ex += d[j];
        }
    }
}

// ---------------- counting-sort edges into CSR (4B src-only entries) ----------
// Weight dis[s]*dis[d] is factored out: dis[s] folded into GEMM epilogue,
// dis[d] folded into aggregate epilogue -> entry is just the src index.
__global__ __launch_bounds__(256) void csr_fill_kernel(const int* __restrict__ ei, int E,
                                                       int* __restrict__ cursor_p,
                                                       int* __restrict__ csr_src) {
    int e = (blockIdx.x * 256 + threadIdx.x) * 2;
    if (e + 1 < E) {
        int s0 = ei[e], s1 = ei[e + 1];
        int d0 = ei[E + e], d1 = ei[E + e + 1];
        int pos0 = atomicAdd(&cursor_p[(size_t)d0 * PAD], 1);
        int pos1 = atomicAdd(&cursor_p[(size_t)d1 * PAD], 1);
        csr_src[pos0] = s0;
        csr_src[pos1] = s1;
    } else if (e < E) {
        int s = ei[e], d = ei[E + e];
        int pos = atomicAdd(&cursor_p[(size_t)d * PAD], 1);
        csr_src[pos] = s;
    }
}

// ---------------- bf16 MFMA GEMM: H[M x NOUT] = dis[m] * (A[M x 128] * W[128 x NOUT]) ----
// AFP32: A is fp32 (layer 1 reads x directly, converts in-register)
template <int NOUT, bool AFP32>
__global__ __launch_bounds__(256) void gemm_bf16_kernel(const void* __restrict__ Av,
                                                        const unsigned short* __restrict__ Wt,
                                                        const float* __restrict__ dis,
                                                        unsigned short* __restrict__ H, int M) {
    int wave = (blockIdx.x * 256 + threadIdx.x) >> 6;
    int lane = threadIdx.x & 63;
    int m0 = wave << 4;
    if (m0 >= M) return;                  // M divisible by 16
    int m = lane & 15, q = lane >> 4;
    constexpr int NT = NOUT / 16;
    f32x4 acc[NT];
    #pragma unroll
    for (int t = 0; t < NT; t++) acc[t] = (f32x4){0.f, 0.f, 0.f, 0.f};
    const short8* Arow = (const short8*)((const unsigned short*)Av + (size_t)(m0 + m) * 128);
    const float*  Arow32 = (const float*)Av + (size_t)(m0 + m) * 128;
    #pragma unroll
    for (int kk = 0; kk < 4; kk++) {
        short8 a;
        if (AFP32) {
            float4 u = *(const float4*)(Arow32 + kk * 32 + q * 8);
            float4 v = *(const float4*)(Arow32 + kk * 32 + q * 8 + 4);
            a[0] = (short)f2bf(u.x); a[1] = (short)f2bf(u.y);
            a[2] = (short)f2bf(u.z); a[3] = (short)f2bf(u.w);
            a[4] = (short)f2bf(v.x); a[5] = (short)f2bf(v.y);
            a[6] = (short)f2bf(v.z); a[7] = (short)f2bf(v.w);
        } else {
            a = Arow[kk * 4 + q];         // A[m0+m][kk*32 + q*8 .. +7]
        }
        #pragma unroll
        for (int t = 0; t < NT; t++) {
            const short8* Bp = (const short8*)(Wt + (size_t)(t * 16 + m) * 128);
            short8 b = Bp[kk * 4 + q];    // W[kk*32+q*8+j][t*16+m]
            acc[t] = __builtin_amdgcn_mfma_f32_16x16x32_bf16(a, b, acc[t], 0, 0, 0);
        }
    }
    float ds[4];
    #pragma unroll
    for (int r = 0; r < 4; r++) ds[r] = dis[m0 + q * 4 + r];
    #pragma unroll
    for (int t = 0; t < NT; t++)
        #pragma unroll
        for (int r = 0; r < 4; r++)
            H[(size_t)(m0 + q * 4 + r) * NOUT + t * 16 + m] = f2bf(acc[t][r] * ds[r]);
}

// ---------------- CSR aggregation (bf16 H pre-scaled by dis[src], 4B edges) ----------
// out[d] = dis[d] * sum_{s in N(d)} Hs[s] + bias
template <int EPL, bool RELU, bool OUTBF>
__global__ __launch_bounds__(256) void aggregate_kernel(const unsigned short* __restrict__ H,
                                                        const int* __restrict__ row_start,
                                                        const int* __restrict__ csr_src,
                                                        const float* __restrict__ dis,
                                                        const float* __restrict__ bias,
                                                        void* __restrict__ out, int n) {
    int wave = (blockIdx.x * 256 + threadIdx.x) >> 6;
    int lane = threadIdx.x & 63;
    if (wave >= n) return;
    constexpr int F = EPL * 64;
    int c = lane * EPL;
    float acc0 = 0.f, acc1 = 0.f;
    int p0 = row_start[wave], p1 = row_start[wave + 1];
    int p = p0;
    for (; p + 4 <= p1; p += 4) {
        int e0 = csr_src[p],     e1 = csr_src[p + 1];
        int e2 = csr_src[p + 2], e3 = csr_src[p + 3];
        if (EPL == 2) {
            unsigned int h0 = *(const unsigned int*)(H + (size_t)e0 * F + c);
            unsigned int h1 = *(const unsigned int*)(H + (size_t)e1 * F + c);
            unsigned int h2 = *(const unsigned int*)(H + (size_t)e2 * F + c);
            unsigned int h3 = *(const unsigned int*)(H + (size_t)e3 * F + c);
            acc0 += bflo(h0) + bflo(h1);
            acc1 += bfhi(h0) + bfhi(h1);
            acc0 += bflo(h2) + bflo(h3);
            acc1 += bfhi(h2) + bfhi(h3);
        } else {
            unsigned short h0 = H[(size_t)e0 * F + c];
            unsigned short h1 = H[(size_t)e1 * F + c];
            unsigned short h2 = H[(size_t)e2 * F + c];
            unsigned short h3 = H[(size_t)e3 * F + c];
            acc0 += __uint_as_float((unsigned int)h0 << 16)
                  + __uint_as_float((unsigned int)h1 << 16);
            acc0 += __uint_as_float((unsigned int)h2 << 16)
                  + __uint_as_float((unsigned int)h3 << 16);
        }
    }
    for (; p < p1; p++) {
        int e = csr_src[p];
        if (EPL == 2) {
            unsigned int h = *(const unsigned int*)(H + (size_t)e * F + c);
            acc0 += bflo(h); acc1 += bfhi(h);
        } else {
            unsigned short h = H[(size_t)e * F + c];
            acc0 += __uint_as_float((unsigned int)h << 16);
        }
    }
    float dd = dis[wave];
    acc0 = acc0 * dd + bias[c];
    if (EPL == 2) acc1 = acc1 * dd + bias[c + 1];
    if (RELU) { acc0 = fmaxf(acc0, 0.f); if (EPL == 2) acc1 = fmaxf(acc1, 0.f); }
    if (OUTBF) {
        unsigned short* ob = (unsigned short*)out + (size_t)wave * F;
        if (EPL == 2) { ushort2 r; r.x = f2bf(acc0); r.y = f2bf(acc1); ((ushort2*)ob)[lane] = r; }
        else ob[c] = f2bf(acc0);
    } else {
        float* of = (float*)out + (size_t)wave * F;
        if (EPL == 2) { ((float2*)of)[lane] = make_float2(acc0, acc1); }
        else of[c] = acc0;
    }
}

// ---------------- decode: hidden = z[a]*z[b]; logits = sum; normalize ----------------
__global__ __launch_bounds__(256) void decode_kernel(const float* __restrict__ Z,
                                                     const int* __restrict__ eli, int EL,
                                                     float* __restrict__ out_h,
                                                     float* __restrict__ out_l) {
    int wave = (blockIdx.x * 256 + threadIdx.x) >> 6;
    int lane = threadIdx.x & 63;
    if (wave >= EL) return;
    int a = eli[wave], b = eli[EL + wave];
    float h = Z[(size_t)a * 64 + lane] * Z[(size_t)b * 64 + lane];
    float s = h, ss = h * h;
    #pragma unroll
    for (int off = 32; off > 0; off >>= 1) {
        s  += __shfl_xor(s, off, 64);
        ss += __shfl_xor(ss, off, 64);
    }
    float nrm = fmaxf(sqrtf(ss), 1e-12f);
    out_h[(size_t)wave * 64 + lane] = h / nrm;
    if (lane == 0) out_l[wave] = s;
}

extern "C" void kernel_launch(void* const* d_in, const int* in_sizes, int n_in,
                              void* d_out, int out_size, void* d_ws, size_t ws_size,
                              hipStream_t stream) {
    const float* x  = (const float*)d_in[0];
    const float* W1 = (const float*)d_in[1];
    const float* b1 = (const float*)d_in[2];
    const float* W2 = (const float*)d_in[3];
    const float* b2 = (const float*)d_in[4];
    const float* W3 = (const float*)d_in[5];
    const float* b3 = (const float*)d_in[6];
    const int* edge_index = (const int*)d_in[7];
    const int* eli        = (const int*)d_in[8];

    const int N  = in_sizes[0] / DIN;
    const int E  = in_sizes[7] / 2;
    const int EL = in_sizes[8] / 2;

    char* w = (char*)d_ws;
    auto alloc = [&](size_t bytes) -> char* {
        char* p = w; w += (bytes + 255) & ~(size_t)255; return p;
    };
    unsigned short* bufA  = (unsigned short*)alloc((size_t)N * DH * 2);  // H1/H2/H3 (bf16)
    float*          Z3    = (float*)alloc((size_t)N * DOUT * 4);         // fp32 final embeddings
    unsigned short* Xbf   = (unsigned short*)alloc((size_t)N * DH * 2);  // bf16 activations
    unsigned short* Wt1   = (unsigned short*)alloc(128 * 128 * 2);
    unsigned short* Wt2   = (unsigned short*)alloc(128 * 128 * 2);
    unsigned short* Wt3   = (unsigned short*)alloc(64 * 128 * 2);
    int*            deg_p = (int*)alloc((size_t)N * PAD * 4);            // padded counters
    int*            row_start = (int*)alloc((size_t)(N + 1) * 4);
    int*            cursor_p = (int*)alloc((size_t)N * PAD * 4);         // padded cursors
    float*          dis    = (float*)alloc((size_t)N * 4);
    int*            bsum   = (int*)alloc(1024);
    int*            csr_src = (int*)alloc((size_t)(E + N) * 4);

    float* out_h = (float*)d_out;
    float* out_l = out_h + (size_t)EL * DOUT;

    const int NB = (N + 1023) / 1024;   // scan blocks (98 for N=100000, <=256 required)
    const int E2 = (E + 1) / 2;         // 2 edges per thread

    // --- build CSR ---
    prep_w_kernel<<<64, 256, 0, stream>>>(W1, W2, W3, Wt1, Wt2, Wt3);
    deg_init_kernel<<<(N + 255) / 256, 256, 0, stream>>>(deg_p, N);
    deg_count_kernel<<<(E2 + 255) / 256, 256, 0, stream>>>(edge_index, E, deg_p);
    scan_block_sums<<<NB, 256, 0, stream>>>(deg_p, bsum, N);
    scan_bsum_kernel<<<1, 256, 0, stream>>>(bsum, NB);
    scan_final_kernel<<<NB, 256, 0, stream>>>(deg_p, bsum, row_start, dis, cursor_p, csr_src, N);
    csr_fill_kernel<<<(E2 + 255) / 256, 256, 0, stream>>>(edge_index, E, cursor_p, csr_src);

    const int gemm_grid = ((N / 16) * 64 + 255) / 256;
    const int agg_grid  = (N + 3) / 4;

    // --- layer 1 (reads fp32 x directly) ---
    gemm_bf16_kernel<128, true><<<gemm_grid, 256, 0, stream>>>(x, Wt1, dis, bufA, N);
    aggregate_kernel<2, true, true><<<agg_grid, 256, 0, stream>>>(bufA, row_start, csr_src, dis, b1, Xbf, N);
    // --- layer 2 ---
    gemm_bf16_kernel<128, false><<<gemm_grid, 256, 0, stream>>>(Xbf, Wt2, dis, bufA, N);
    aggregate_kernel<2, true, true><<<agg_grid, 256, 0, stream>>>(bufA, row_start, csr_src, dis, b2, Xbf, N);
    // --- layer 3 ---
    gemm_bf16_kernel<64, false><<<gemm_grid, 256, 0, stream>>>(Xbf, Wt3, dis, bufA, N);
    aggregate_kernel<1, false, false><<<agg_grid, 256, 0, stream>>>(bufA, row_start, csr_src, dis, b3, Z3, N);
    // --- decode ---
    decode_kernel<<<(EL + 3) / 4, 256, 0, stream>>>(Z3, eli, EL, out_h, out_l);
}

// Round 2
// 522.630 us; speedup vs baseline: 1.2857x; 1.2857x over previous
//
#include <hip/hip_runtime.h>
#include <hip/hip_bf16.h>

#define DIN 128
#define DH  128
#define DOUT 64

// bucketed CSR build: 512 nodes per bucket (dst >> 9), N=100000 -> 196 buckets
#define BSHIFT 9
#define BNODES 512
#define BCAP   12288      // capacity per bucket (mean 8192, sigma ~90 -> 45 sigma margin)
#define CHUNK  4096       // edges per bin_scatter workgroup (16 per thread)

typedef __attribute__((ext_vector_type(8))) short short8;
typedef __attribute__((ext_vector_type(4))) float f32x4;

static __device__ __forceinline__ unsigned short f2bf(float f) {
    unsigned int u = __float_as_uint(f);
    u += 0x7FFFu + ((u >> 16) & 1u);   // RNE
    return (unsigned short)(u >> 16);
}
static __device__ __forceinline__ float bflo(unsigned int p) {
    return __uint_as_float(p << 16);
}
static __device__ __forceinline__ float bfhi(unsigned int p) {
    return __uint_as_float(p & 0xFFFF0000u);
}

// ---------------- weights: transpose + cast to bf16 (also zeroes bucket cursors) ----
__global__ __launch_bounds__(256) void prep_w_kernel(const float* __restrict__ W1,
                                                     const float* __restrict__ W2,
                                                     const float* __restrict__ W3,
                                                     unsigned short* __restrict__ Wt1,
                                                     unsigned short* __restrict__ Wt2,
                                                     unsigned short* __restrict__ Wt3,
                                                     int* __restrict__ gcur) {
    int i = blockIdx.x * 256 + threadIdx.x;
    if (blockIdx.x == 0) gcur[threadIdx.x] = 0;
    if (i < 128 * 128) {
        int n = i >> 7, k = i & 127;
        Wt1[n * 128 + k] = f2bf(W1[k * 128 + n]);
        Wt2[n * 128 + k] = f2bf(W2[k * 128 + n]);
        if (n < 64) Wt3[n * 128 + k] = f2bf(W3[k * 64 + n]);
    }
}

// ---------------- pass A: multisplit edges into dst-buckets ----------------
// entry = (dst_local << 17) | src   (src < 2^17, dst_local < 512)
__global__ __launch_bounds__(256) void bin_scatter_kernel(const int* __restrict__ ei, int E,
                                                          int* __restrict__ gcur,
                                                          int* __restrict__ pairs) {
    __shared__ int hist[256];
    __shared__ int base[256];
    int t = threadIdx.x;
    hist[t] = 0;
    __syncthreads();
    int e0 = blockIdx.x * CHUNK;
    int srcs[16], dsts[16], rk[16];
    #pragma unroll
    for (int j = 0; j < 16; j++) {
        int e = e0 + j * 256 + t;
        if (e < E) {
            srcs[j] = ei[e];
            dsts[j] = ei[E + e];
            rk[j] = atomicAdd(&hist[dsts[j] >> BSHIFT], 1);
        } else {
            rk[j] = -1;
        }
    }
    __syncthreads();
    base[t] = (hist[t] > 0) ? atomicAdd(&gcur[t], hist[t]) : 0;
    __syncthreads();
    #pragma unroll
    for (int j = 0; j < 16; j++) {
        if (rk[j] >= 0) {
            int b = dsts[j] >> BSHIFT;
            int dl = dsts[j] & (BNODES - 1);
            pairs[(size_t)b * BCAP + base[b] + rk[j]] = (dl << 17) | srcs[j];
        }
    }
}

// ---------------- pass B: per-bucket degree via LDS counters ----------------
__global__ __launch_bounds__(256) void bucket_deg_kernel(const int* __restrict__ pairs,
                                                         const int* __restrict__ gcur,
                                                         int* __restrict__ deg, int n) {
    __shared__ int cnt_l[BNODES];
    int t = threadIdx.x, b = blockIdx.x;
    cnt_l[t] = 0; cnt_l[t + 256] = 0;
    __syncthreads();
    int cnt = gcur[b];
    const int* p = pairs + (size_t)b * BCAP;
    for (int i = t; i < cnt; i += 256) {
        int pk = p[i];
        atomicAdd(&cnt_l[pk >> 17], 1);
    }
    __syncthreads();
    int node = (b << BSHIFT) + t;
    if (node < n) deg[node] = cnt_l[t] + 1;               // +1 self-loop
    node += 256;
    if (node < n) deg[node] = cnt_l[t + 256] + 1;
}

// ---------------- 3-phase exclusive scan of deg -> row_start ----------------
__global__ __launch_bounds__(256) void scan_block_sums(const int* __restrict__ deg,
                                                       int* __restrict__ bsum, int n) {
    __shared__ int s[256];
    int t = threadIdx.x, base = blockIdx.x * 1024;
    int v = 0;
    #pragma unroll
    for (int j = 0; j < 4; j++) {
        int idx = base + t * 4 + j;
        if (idx < n) v += deg[idx];
    }
    s[t] = v; __syncthreads();
    for (int off = 128; off > 0; off >>= 1) {
        if (t < off) s[t] += s[t + off];
        __syncthreads();
    }
    if (t == 0) bsum[blockIdx.x] = s[0];
}

__global__ __launch_bounds__(256) void scan_bsum_kernel(int* __restrict__ bsum, int nb) {
    __shared__ int s[256];
    int t = threadIdx.x;
    s[t] = (t < nb) ? bsum[t] : 0; __syncthreads();
    for (int off = 1; off < 256; off <<= 1) {
        int v = (t >= off) ? s[t - off] : 0;
        __syncthreads();
        s[t] += v;
        __syncthreads();
    }
    if (t < nb) bsum[t] = (t > 0) ? s[t - 1] : 0;   // exclusive
}

__global__ __launch_bounds__(256) void scan_final_kernel(const int* __restrict__ deg,
                                                         const int* __restrict__ bsum_ex,
                                                         int* __restrict__ row_start,
                                                         float* __restrict__ dis,
                                                         int* __restrict__ csr_src, int n) {
    __shared__ int s[256];
    int t = threadIdx.x, base = blockIdx.x * 1024;
    int d[4]; int local = 0;
    #pragma unroll
    for (int j = 0; j < 4; j++) {
        int idx = base + t * 4 + j;
        d[j] = (idx < n) ? deg[idx] : 0;
        local += d[j];
    }
    s[t] = local; __syncthreads();
    for (int off = 1; off < 256; off <<= 1) {
        int v = (t >= off) ? s[t - off] : 0;
        __syncthreads();
        s[t] += v;
        __syncthreads();
    }
    int ex = ((t > 0) ? s[t - 1] : 0) + bsum_ex[blockIdx.x];
    #pragma unroll
    for (int j = 0; j < 4; j++) {
        int idx = base + t * 4 + j;
        if (idx < n) {
            row_start[idx] = ex;
            float di = rsqrtf((float)d[j]);
            dis[idx] = di;
            csr_src[ex] = idx;                      // self-loop entry (src = idx)
            if (idx == n - 1) row_start[n] = ex + d[j];
            ex += d[j];
        }
    }
}

// ---------------- pass C: per-bucket CSR fill via LDS cursors ----------------
__global__ __launch_bounds__(256) void bucket_fill_kernel(const int* __restrict__ pairs,
                                                          const int* __restrict__ gcur,
                                                          const int* __restrict__ row_start,
                                                          int* __restrict__ csr_src, int n) {
    __shared__ int cur[BNODES];
    int t = threadIdx.x, b = blockIdx.x;
    int node = (b << BSHIFT) + t;
    cur[t] = (node < n) ? row_start[node] + 1 : 0;        // slot 0 = self loop
    int node2 = node + 256;
    cur[t + 256] = (node2 < n) ? row_start[node2] + 1 : 0;
    __syncthreads();
    int cnt = gcur[b];
    const int* p = pairs + (size_t)b * BCAP;
    for (int i = t; i < cnt; i += 256) {
        int pk = p[i];
        int pos = atomicAdd(&cur[pk >> 17], 1);
        csr_src[pos] = pk & 0x1FFFF;
    }
}

// ---------------- bf16 MFMA GEMM: H[M x NOUT] = dis[m] * (A[M x 128] * W[128 x NOUT]) ----
// AFP32: A is fp32 (layer 1 reads x directly, converts in-register)
template <int NOUT, bool AFP32>
__global__ __launch_bounds__(256) void gemm_bf16_kernel(const void* __restrict__ Av,
                                                        const unsigned short* __restrict__ Wt,
                                                        const float* __restrict__ dis,
                                                        unsigned short* __restrict__ H, int M) {
    int wave = (blockIdx.x * 256 + threadIdx.x) >> 6;
    int lane = threadIdx.x & 63;
    int m0 = wave << 4;
    if (m0 >= M) return;                  // M divisible by 16
    int m = lane & 15, q = lane >> 4;
    constexpr int NT = NOUT / 16;
    f32x4 acc[NT];
    #pragma unroll
    for (int t = 0; t < NT; t++) acc[t] = (f32x4){0.f, 0.f, 0.f, 0.f};
    const short8* Arow = (const short8*)((const unsigned short*)Av + (size_t)(m0 + m) * 128);
    const float*  Arow32 = (const float*)Av + (size_t)(m0 + m) * 128;
    #pragma unroll
    for (int kk = 0; kk < 4; kk++) {
        short8 a;
        if (AFP32) {
            float4 u = *(const float4*)(Arow32 + kk * 32 + q * 8);
            float4 v = *(const float4*)(Arow32 + kk * 32 + q * 8 + 4);
            a[0] = (short)f2bf(u.x); a[1] = (short)f2bf(u.y);
            a[2] = (short)f2bf(u.z); a[3] = (short)f2bf(u.w);
            a[4] = (short)f2bf(v.x); a[5] = (short)f2bf(v.y);
            a[6] = (short)f2bf(v.z); a[7] = (short)f2bf(v.w);
        } else {
            a = Arow[kk * 4 + q];         // A[m0+m][kk*32 + q*8 .. +7]
        }
        #pragma unroll
        for (int t = 0; t < NT; t++) {
            const short8* Bp = (const short8*)(Wt + (size_t)(t * 16 + m) * 128);
            short8 b = Bp[kk * 4 + q];    // W[kk*32+q*8+j][t*16+m]
            acc[t] = __builtin_amdgcn_mfma_f32_16x16x32_bf16(a, b, acc[t], 0, 0, 0);
        }
    }
    float ds[4];
    #pragma unroll
    for (int r = 0; r < 4; r++) ds[r] = dis[m0 + q * 4 + r];
    #pragma unroll
    for (int t = 0; t < NT; t++)
        #pragma unroll
        for (int r = 0; r < 4; r++)
            H[(size_t)(m0 + q * 4 + r) * NOUT + t * 16 + m] = f2bf(acc[t][r] * ds[r]);
}

// ---------------- CSR aggregation (bf16 H pre-scaled by dis[src], 4B edges) ----------
// out[d] = dis[d] * sum_{s in N(d)} Hs[s] + bias
template <int EPL, bool RELU, bool OUTBF>
__global__ __launch_bounds__(256) void aggregate_kernel(const unsigned short* __restrict__ H,
                                                        const int* __restrict__ row_start,
                                                        const int* __restrict__ csr_src,
                                                        const float* __restrict__ dis,
                                                        const float* __restrict__ bias,
                                                        void* __restrict__ out, int n) {
    int wave = (blockIdx.x * 256 + threadIdx.x) >> 6;
    int lane = threadIdx.x & 63;
    if (wave >= n) return;
    constexpr int F = EPL * 64;
    int c = lane * EPL;
    float acc0 = 0.f, acc1 = 0.f;
    int p0 = row_start[wave], p1 = row_start[wave + 1];
    int p = p0;
    for (; p + 4 <= p1; p += 4) {
        int e0 = csr_src[p],     e1 = csr_src[p + 1];
        int e2 = csr_src[p + 2], e3 = csr_src[p + 3];
        if (EPL == 2) {
            unsigned int h0 = *(const unsigned int*)(H + (size_t)e0 * F + c);
            unsigned int h1 = *(const unsigned int*)(H + (size_t)e1 * F + c);
            unsigned int h2 = *(const unsigned int*)(H + (size_t)e2 * F + c);
            unsigned int h3 = *(const unsigned int*)(H + (size_t)e3 * F + c);
            acc0 += bflo(h0) + bflo(h1);
            acc1 += bfhi(h0) + bfhi(h1);
            acc0 += bflo(h2) + bflo(h3);
            acc1 += bfhi(h2) + bfhi(h3);
        } else {
            unsigned short h0 = H[(size_t)e0 * F + c];
            unsigned short h1 = H[(size_t)e1 * F + c];
            unsigned short h2 = H[(size_t)e2 * F + c];
            unsigned short h3 = H[(size_t)e3 * F + c];
            acc0 += __uint_as_float((unsigned int)h0 << 16)
                  + __uint_as_float((unsigned int)h1 << 16);
            acc0 += __uint_as_float((unsigned int)h2 << 16)
                  + __uint_as_float((unsigned int)h3 << 16);
        }
    }
    for (; p < p1; p++) {
        int e = csr_src[p];
        if (EPL == 2) {
            unsigned int h = *(const unsigned int*)(H + (size_t)e * F + c);
            acc0 += bflo(h); acc1 += bfhi(h);
        } else {
            unsigned short h = H[(size_t)e * F + c];
            acc0 += __uint_as_float((unsigned int)h << 16);
        }
    }
    float dd = dis[wave];
    acc0 = acc0 * dd + bias[c];
    if (EPL == 2) acc1 = acc1 * dd + bias[c + 1];
    if (RELU) { acc0 = fmaxf(acc0, 0.f); if (EPL == 2) acc1 = fmaxf(acc1, 0.f); }
    if (OUTBF) {
        unsigned short* ob = (unsigned short*)out + (size_t)wave * F;
        if (EPL == 2) { ushort2 r; r.x = f2bf(acc0); r.y = f2bf(acc1); ((ushort2*)ob)[lane] = r; }
        else ob[c] = f2bf(acc0);
    } else {
        float* of = (float*)out + (size_t)wave * F;
        if (EPL == 2) { ((float2*)of)[lane] = make_float2(acc0, acc1); }
        else of[c] = acc0;
    }
}

// ---------------- decode: hidden = z[a]*z[b]; logits = sum; normalize ----------------
__global__ __launch_bounds__(256) void decode_kernel(const float* __restrict__ Z,
                                                     const int* __restrict__ eli, int EL,
                                                     float* __restrict__ out_h,
                                                     float* __restrict__ out_l) {
    int wave = (blockIdx.x * 256 + threadIdx.x) >> 6;
    int lane = threadIdx.x & 63;
    if (wave >= EL) return;
    int a = eli[wave], b = eli[EL + wave];
    float h = Z[(size_t)a * 64 + lane] * Z[(size_t)b * 64 + lane];
    float s = h, ss = h * h;
    #pragma unroll
    for (int off = 32; off > 0; off >>= 1) {
        s  += __shfl_xor(s, off, 64);
        ss += __shfl_xor(ss, off, 64);
    }
    float nrm = fmaxf(sqrtf(ss), 1e-12f);
    out_h[(size_t)wave * 64 + lane] = h / nrm;
    if (lane == 0) out_l[wave] = s;
}

extern "C" void kernel_launch(void* const* d_in, const int* in_sizes, int n_in,
                              void* d_out, int out_size, void* d_ws, size_t ws_size,
                              hipStream_t stream) {
    const float* x  = (const float*)d_in[0];
    const float* W1 = (const float*)d_in[1];
    const float* b1 = (const float*)d_in[2];
    const float* W2 = (const float*)d_in[3];
    const float* b2 = (const float*)d_in[4];
    const float* W3 = (const float*)d_in[5];
    const float* b3 = (const float*)d_in[6];
    const int* edge_index = (const int*)d_in[7];
    const int* eli        = (const int*)d_in[8];

    const int N  = in_sizes[0] / DIN;
    const int E  = in_sizes[7] / 2;
    const int EL = in_sizes[8] / 2;
    const int NBUCK = (N + BNODES - 1) >> BSHIFT;   // 196 for N=100000 (<=256 required)

    char* w = (char*)d_ws;
    auto alloc = [&](size_t bytes) -> char* {
        char* p = w; w += (bytes + 255) & ~(size_t)255; return p;
    };
    unsigned short* bufA  = (unsigned short*)alloc((size_t)N * DH * 2);  // H1/H2/H3 (bf16)
    float*          Z3    = (float*)alloc((size_t)N * DOUT * 4);         // fp32 final embeddings
    unsigned short* Xbf   = (unsigned short*)alloc((size_t)N * DH * 2);  // bf16 activations
    unsigned short* Wt1   = (unsigned short*)alloc(128 * 128 * 2);
    unsigned short* Wt2   = (unsigned short*)alloc(128 * 128 * 2);
    unsigned short* Wt3   = (unsigned short*)alloc(64 * 128 * 2);
    int*            deg   = (int*)alloc((size_t)N * 4);                  // dense degrees
    int*            row_start = (int*)alloc((size_t)(N + 1) * 4);
    float*          dis    = (float*)alloc((size_t)N * 4);
    int*            bsum   = (int*)alloc(1024);
    int*            gcur   = (int*)alloc(256 * 4);                       // bucket cursors
    int*            csr_src = (int*)alloc((size_t)(E + N) * 4);
    int*            pairs  = (int*)alloc((size_t)NBUCK * BCAP * 4);      // bucketed edges

    float* out_h = (float*)d_out;
    float* out_l = out_h + (size_t)EL * DOUT;

    const int NB = (N + 1023) / 1024;   // scan blocks (98 for N=100000, <=256 required)

    // --- build CSR (bucketed multisplit) ---
    prep_w_kernel<<<64, 256, 0, stream>>>(W1, W2, W3, Wt1, Wt2, Wt3, gcur);
    bin_scatter_kernel<<<(E + CHUNK - 1) / CHUNK, 256, 0, stream>>>(edge_index, E, gcur, pairs);
    bucket_deg_kernel<<<NBUCK, 256, 0, stream>>>(pairs, gcur, deg, N);
    scan_block_sums<<<NB, 256, 0, stream>>>(deg, bsum, N);
    scan_bsum_kernel<<<1, 256, 0, stream>>>(bsum, NB);
    scan_final_kernel<<<NB, 256, 0, stream>>>(deg, bsum, row_start, dis, csr_src, N);
    bucket_fill_kernel<<<NBUCK, 256, 0, stream>>>(pairs, gcur, row_start, csr_src, N);

    const int gemm_grid = ((N / 16) * 64 + 255) / 256;
    const int agg_grid  = (N + 3) / 4;

    // --- layer 1 (reads fp32 x directly) ---
    gemm_bf16_kernel<128, true><<<gemm_grid, 256, 0, stream>>>(x, Wt1, dis, bufA, N);
    aggregate_kernel<2, true, true><<<agg_grid, 256, 0, stream>>>(bufA, row_start, csr_src, dis, b1, Xbf, N);
    // --- layer 2 ---
    gemm_bf16_kernel<128, false><<<gemm_grid, 256, 0, stream>>>(Xbf, Wt2, dis, bufA, N);
    aggregate_kernel<2, true, true><<<agg_grid, 256, 0, stream>>>(bufA, row_start, csr_src, dis, b2, Xbf, N);
    // --- layer 3 ---
    gemm_bf16_kernel<64, false><<<gemm_grid, 256, 0, stream>>>(Xbf, Wt3, dis, bufA, N);
    aggregate_kernel<1, false, false><<<agg_grid, 256, 0, stream>>>(bufA, row_start, csr_src, dis, b3, Z3, N);
    // --- decode ---
    decode_kernel<<<(EL + 3) / 4, 256, 0, stream>>>(Z3, eli, EL, out_h, out_l);
}